// Round 3
// baseline (884.509 us; speedup 1.0000x reference)
//
#include <hip/hip_runtime.h>
#include <math.h>

// SOCPooling on MI355X (gfx950):
//   x [128,1024,768] f32, W [24,768] f32 -> out [128,300] f32
// k1: projection p = x W^T fused with per-block partial S = P^T P and s = sum(p)
//     (deterministic per-block partials in ws; no atomics, no memset needed).
// k2: combine partials -> centered cov -> trace-norm+sym+ridge -> one-sided
//     Jacobi eigh (lane j holds column j in 24 VGPRs, shfl partner exchange,
//     circle-method disjoint pairing, incremental diagonal, early exit)
//     -> V log(L) V^T upper triangle.

#define B_      128
#define T_      1024
#define D_      768
#define K_      24
#define ROWS    256      // rows per k1 block
#define BPB     4        // k1 blocks per batch
#define DCHUNK  32
#define NLD     8        // float4 global loads per thread per chunk
#define LSTRIDE 36       // x-tile LDS row stride (words); 144B rows, 16B aligned
#define PSTRIDE 28       // P-tile row stride; 112B rows, 16B aligned for b128
#define NACC    600      // 576 S entries + 24 sums
#define NPAIR   300
#define SWEEPS  10       // cap; early exit typically ~5

__global__ __launch_bounds__(256, 2) void socpool_proj(
    const float* __restrict__ x, const float* __restrict__ W,
    float* __restrict__ partial) {
  __shared__ float smem[ROWS * LSTRIDE];  // 36864 B; reused as P[256][28]
  const int tid = threadIdx.x;
  const int b  = blockIdx.x >> 2;
  const int rb = blockIdx.x & 3;
  const float* xbase = x + ((size_t)b * T_ + rb * ROWS) * D_;
  // staging geometry: thread -> (row r0 + 32*it, dims j4..j4+3)
  const int r0 = tid >> 3;
  const int j4 = (tid & 7) * 4;
  const float* gp = xbase + (size_t)r0 * D_ + j4;
  const int lbase = r0 * LSTRIDE + j4;

  float acc[K_];
#pragma unroll
  for (int k = 0; k < K_; ++k) acc[k] = 0.f;

  // prefetch chunk 0 into registers
  float4 pre[NLD];
#pragma unroll
  for (int it = 0; it < NLD; ++it)
    pre[it] = *(const float4*)(gp + (size_t)it * 32 * D_);

  for (int dc = 0; dc < D_; dc += DCHUNK) {
    __syncthreads();  // previous chunk's LDS reads complete
#pragma unroll
    for (int it = 0; it < NLD; ++it)
      *(float4*)(&smem[lbase + it * 32 * LSTRIDE]) = pre[it];
    __syncthreads();
    // issue next chunk's global loads now; consumed next iteration (latency
    // hidden under this chunk's 768 FMAs)
    if (dc + DCHUNK < D_) {
#pragma unroll
      for (int it = 0; it < NLD; ++it)
        pre[it] = *(const float4*)(gp + (dc + DCHUNK) + (size_t)it * 32 * D_);
    }
    // thread tid owns row tid; W offsets wave-uniform -> scalar loads
#pragma unroll
    for (int d = 0; d < DCHUNK; d += 4) {
      float4 xv = *(const float4*)(&smem[tid * LSTRIDE + d]);
      const float* wp = W + dc + d;
#pragma unroll
      for (int k = 0; k < K_; ++k) {
        const float* wr = wp + (size_t)k * D_;
        acc[k] = fmaf(xv.x, wr[0], acc[k]);
        acc[k] = fmaf(xv.y, wr[1], acc[k]);
        acc[k] = fmaf(xv.z, wr[2], acc[k]);
        acc[k] = fmaf(xv.w, wr[3], acc[k]);
      }
    }
  }
  __syncthreads();
  float* P = smem;  // 256*28*4 = 28672 B
#pragma unroll
  for (int q = 0; q < 6; ++q)
    *(float4*)(&P[tid * PSTRIDE + 4 * q]) =
        make_float4(acc[4*q], acc[4*q+1], acc[4*q+2], acc[4*q+3]);
  __syncthreads();
  // per-block partial S[k][l] (full 24x24, quad tasks) and column sums
  float* outp = partial + (size_t)blockIdx.x * NACC;
  if (tid < 144) {
    const int k = tid / 6;
    const int q = (tid % 6) * 4;
    float a0=0.f,a1=0.f,a2=0.f,a3=0.f,b0=0.f,b1=0.f,b2=0.f,b3=0.f;
    for (int t = 0; t < ROWS; t += 2) {
      float  pk0 = P[t * PSTRIDE + k];
      float4 pq0 = *(const float4*)(&P[t * PSTRIDE + q]);
      float  pk1 = P[(t + 1) * PSTRIDE + k];
      float4 pq1 = *(const float4*)(&P[(t + 1) * PSTRIDE + q]);
      a0 = fmaf(pk0, pq0.x, a0); a1 = fmaf(pk0, pq0.y, a1);
      a2 = fmaf(pk0, pq0.z, a2); a3 = fmaf(pk0, pq0.w, a3);
      b0 = fmaf(pk1, pq1.x, b0); b1 = fmaf(pk1, pq1.y, b1);
      b2 = fmaf(pk1, pq1.z, b2); b3 = fmaf(pk1, pq1.w, b3);
    }
    outp[k * K_ + q + 0] = a0 + b0;
    outp[k * K_ + q + 1] = a1 + b1;
    outp[k * K_ + q + 2] = a2 + b2;
    outp[k * K_ + q + 3] = a3 + b3;
  } else if (tid < 168) {
    const int k = tid - 144;
    float s0 = 0.f, s1 = 0.f;
    for (int t = 0; t < ROWS; t += 2) {
      s0 += P[t * PSTRIDE + k];
      s1 += P[(t + 1) * PSTRIDE + k];
    }
    outp[576 + k] = s0 + s1;
  }
}

__global__ __launch_bounds__(64, 1) void socpool_eig(
    const float* __restrict__ partial, float* __restrict__ out) {
  __shared__ float Amat[K_ * 25];
  __shared__ float Qs[K_ * 25];
  __shared__ float lv[K_];
  __shared__ float raw[NACC];
  const int tid = threadIdx.x;  // 64 threads
  const int b = blockIdx.x;

  // combine the 4 per-block partials
#pragma unroll
  for (int i = 0; i < 10; ++i) {
    int e = tid + (i << 6);
    if (e < NACC) {
      float v = 0.f;
#pragma unroll
      for (int jj = 0; jj < BPB; ++jj)
        v += partial[(size_t)(b * BPB + jj) * NACC + e];
      raw[e] = v;
    }
  }
  __syncthreads();

  const float inv_n   = 1.f / 1024.f;
  const float inv_nm1 = 1.f / (1023.f + 1e-6f);
  float cv[9];
#pragma unroll
  for (int i = 0; i < 9; ++i) {
    int e = tid + (i << 6);            // < 576 always
    int k = e / K_, l = e % K_;
    cv[i] = (raw[e] - raw[576 + k] * raw[576 + l] * inv_n) * inv_nm1;
    Amat[k * 25 + l] = cv[i];
  }
  __syncthreads();
  float tr = 0.f;
#pragma unroll
  for (int k = 0; k < K_; ++k) tr += Amat[k * 25 + k];
  float sym[9];
#pragma unroll
  for (int i = 0; i < 9; ++i) {
    int e = tid + (i << 6);
    int k = e / K_, l = e % K_;
    sym[i] = cv[i] + Amat[l * 25 + k];
  }
  __syncthreads();
  const float sc = 0.5f / (tr + 1e-6f);
#pragma unroll
  for (int i = 0; i < 9; ++i) {
    int e = tid + (i << 6);
    int k = e / K_, l = e % K_;
    Amat[k * 25 + l] = sym[i] * sc + ((k == l) ? 1e-4f : 0.f);
  }
  __syncthreads();

  // ---- one-sided Jacobi: lane j holds column j ----
  const int j = tid;
  float G[K_];
#pragma unroll
  for (int r = 0; r < K_; ++r)
    G[r] = (j < K_) ? Amat[r * 25 + j] : 0.f;

  float nn = 0.f;
  for (int sweep = 0; sweep < SWEEPS; ++sweep) {
    {  // refresh own Gram diagonal once per sweep
      float n0=0.f,n1=0.f,n2=0.f,n3=0.f;
#pragma unroll
      for (int r = 0; r < K_; r += 4) {
        n0 = fmaf(G[r],   G[r],   n0);
        n1 = fmaf(G[r+1], G[r+1], n1);
        n2 = fmaf(G[r+2], G[r+2], n2);
        n3 = fmaf(G[r+3], G[r+3], n3);
      }
      nn = (n0 + n1) + (n2 + n3);
    }
    float offacc = 0.f;
    for (int rr = 0; rr < 23; ++rr) {
      // circle-method round-robin: fixed player 23; inv(2) mod 23 = 12
      int partner;
      if (j == 23) {
        partner = (12 * rr) % 23;
      } else if (j < 23) {
        partner = rr - j;
        if (partner < 0) partner += 23;
        if (partner == j) partner = 23;
      } else {
        partner = j;  // idle lanes self-pair; rotation skipped below
      }
      float oth[K_];
#pragma unroll
      for (int r = 0; r < K_; ++r) oth[r] = __shfl(G[r], partner, 64);
      float d0=0.f,d1=0.f,d2=0.f,d3=0.f;
#pragma unroll
      for (int r = 0; r < K_; r += 4) {
        d0 = fmaf(G[r],   oth[r],   d0);
        d1 = fmaf(G[r+1], oth[r+1], d1);
        d2 = fmaf(G[r+2], oth[r+2], d2);
        d3 = fmaf(G[r+3], oth[r+3], d3);
      }
      float gpq = (d0 + d1) + (d2 + d3);
      float nno = __shfl(nn, partner, 64);
      const bool low = (j < partner);
      float app = low ? nn : nno;
      float aqq = low ? nno : nn;
      float t = 0.f, cc = 1.f, ss = 0.f;
      if (j != partner && fabsf(gpq) > 1e-30f) {
        float tau = (aqq - app) / (2.f * gpq);
        t = 1.f / (fabsf(tau) + sqrtf(1.f + tau * tau));
        if (tau < 0.f) t = -t;
        cc = 1.f / sqrtf(1.f + t * t);
        ss = t * cc;
      }
      float sg = low ? -ss : ss;  // p' = c p - s q ; q' = s p + c q
#pragma unroll
      for (int r = 0; r < K_; ++r) G[r] = fmaf(sg, oth[r], cc * G[r]);
      nn += low ? (-t * gpq) : (t * gpq);  // a_pp' = a_pp - t a_pq etc.
      if (j < K_) offacc += gpq * gpq;
    }
#pragma unroll
    for (int m = 1; m < 64; m <<= 1) offacc += __shfl_xor(offacc, m, 64);
    if (offacc < 1e-12f) break;
  }

  // eigenvalues = column norms (A SPD), eigenvectors = normalized columns
  if (j < K_) {
    float n0=0.f,n1=0.f;
#pragma unroll
    for (int r = 0; r < K_; r += 2) {
      n0 = fmaf(G[r],   G[r],   n0);
      n1 = fmaf(G[r+1], G[r+1], n1);
    }
    float lam = sqrtf(n0 + n1);
    lv[j] = logf(fmaxf(lam, 1e-6f));
    float inv = 1.f / fmaxf(lam, 1e-20f);
#pragma unroll
    for (int r = 0; r < K_; ++r) Qs[r * 25 + j] = G[r] * inv;
  }
  __syncthreads();

  // log_cov = Q diag(lv) Q^T, upper triangle row-major (matches triu_indices)
  for (int e = tid; e < NPAIR; e += 64) {
    int i = 0, base = 0;
    while (i < K_ - 1 && base + (K_ - i) <= e) { base += K_ - i; ++i; }
    int jj = i + (e - base);
    float sum = 0.f;
#pragma unroll
    for (int k = 0; k < K_; ++k)
      sum = fmaf(Qs[i * 25 + k] * lv[k], Qs[jj * 25 + k], sum);
    out[(size_t)b * NPAIR + e] = sum;
  }
}

extern "C" void kernel_launch(void* const* d_in, const int* in_sizes, int n_in,
                              void* d_out, int out_size, void* d_ws, size_t ws_size,
                              hipStream_t stream) {
  const float* x = (const float*)d_in[0];
  const float* W = (const float*)d_in[1];
  float* partial = (float*)d_ws;  // 512 * 600 * 4 = 1.2 MB
  float* out = (float*)d_out;
  hipLaunchKernelGGL(socpool_proj, dim3(B_ * BPB), dim3(256), 0, stream,
                     x, W, partial);
  hipLaunchKernelGGL(socpool_eig, dim3(B_), dim3(64), 0, stream,
                     partial, out);
}

// Round 4
// 876.748 us; speedup vs baseline: 1.0089x; 1.0089x over previous
//
#include <hip/hip_runtime.h>
#include <math.h>

// SOCPooling on MI355X (gfx950):
//   x [128,1024,768] f32, W [24,768] f32 -> out [128,300] f32
// k1: projection p = x W^T fused with per-block partial S = P^T P, s = sum(p).
//     Async global->LDS staging (global_load_lds dwordx4, double-buffered,
//     XOR-quad swizzle for conflict-free ds_read_b128), W via scalar loads.
// k2: cov finalize + one-sided Jacobi eigh. Column exchange through LDS
//     (6x ds_write_b128 + 6x ds_read_b128 per round instead of 25 serialized
//     ds_bpermute) -> V log(L) V^T upper triangle.

#define AS1 __attribute__((address_space(1)))
#define AS3 __attribute__((address_space(3)))

#define B_      128
#define T_      1024
#define D_      768
#define K_      24
#define ROWS    256      // rows per k1 block
#define BPB     4        // k1 blocks per batch
#define DCHUNK  32
#define CHW     8192     // words per chunk buffer (256 rows * 32 words)
#define PSTRIDE 28       // padded row/col stride (112 B, 16B-aligned)
#define NACC    600      // 576 S entries + 24 sums
#define NPAIR   300
#define SWEEPS  8

__global__ __launch_bounds__(256, 2) void socpool_proj(
    const float* __restrict__ x, const float* __restrict__ W,
    float* __restrict__ partial) {
  __shared__ float smem[2 * CHW];  // 65536 B double buffer; bufA reused as P
  const int tid  = threadIdx.x;
  const int b    = blockIdx.x >> 2;
  const int rb   = blockIdx.x & 3;
  const int wv   = tid >> 6;
  const int lane = tid & 63;
  const float* xbase = x + ((size_t)b * T_ + rb * ROWS) * D_;

  float acc[K_];
#pragma unroll
  for (int k = 0; k < K_; ++k) acc[k] = 0.f;

  // Async staging. Flat float4 index fl = it*256 + wv*64 + lane.
  // LDS word offset = fl*4 (wave-uniform base + lane*16B, as HW requires).
  // Storage quad q = fl&7 of row fl>>3 holds LOGICAL quad (q ^ (row&7)):
  // the swizzle is applied on the per-lane GLOBAL address, so compute-side
  // ds_read_b128 at word tid*32 + ((qd^(tid&7))<<2) is bank-conflict-free.
  auto issue = [&](int dc, int bufsel) {
    float* buf = smem + bufsel * CHW;
#pragma unroll
    for (int it = 0; it < 8; ++it) {
      const int fl  = it * 256 + wv * 64 + lane;
      const int row = fl >> 3;
      const int qlg = (fl & 7) ^ (row & 7);
      const float* g = xbase + (size_t)row * D_ + (dc + (qlg << 2));
      float* l = buf + (size_t)(it * 256 + wv * 64) * 4;  // wave-uniform
      __builtin_amdgcn_global_load_lds((const AS1 void*)g, (AS3 void*)l,
                                       16, 0, 0);
    }
  };

  issue(0, 0);
  __syncthreads();  // drains vmcnt: chunk 0 resident
  for (int c = 0; c < D_ / DCHUNK; ++c) {
    if (c + 1 < D_ / DCHUNK) issue((c + 1) * DCHUNK, (c + 1) & 1);
    const float* buf = smem + (c & 1) * CHW;
    const int dc = c * DCHUNK;
    // thread tid owns row tid; W offsets wave-uniform -> scalar loads
#pragma unroll
    for (int qd = 0; qd < 8; ++qd) {
      float4 xv = *(const float4*)(&buf[tid * 32 + ((qd ^ (tid & 7)) << 2)]);
      const float* wp = W + dc + (qd << 2);
#pragma unroll
      for (int k = 0; k < K_; ++k) {
        const float* wr = wp + (size_t)k * D_;
        acc[k] = fmaf(xv.x, wr[0], acc[k]);
        acc[k] = fmaf(xv.y, wr[1], acc[k]);
        acc[k] = fmaf(xv.z, wr[2], acc[k]);
        acc[k] = fmaf(xv.w, wr[3], acc[k]);
      }
    }
    __syncthreads();  // chunk c+1 loads drained; buffer reuse guarded
  }

  float* P = smem;  // 256*28*4 = 28672 B, fits in bufA
#pragma unroll
  for (int q = 0; q < 6; ++q)
    *(float4*)(&P[tid * PSTRIDE + 4 * q]) =
        make_float4(acc[4*q], acc[4*q+1], acc[4*q+2], acc[4*q+3]);
  __syncthreads();
  // per-block partial S[k][l] (full 24x24, quad tasks) and column sums
  float* outp = partial + (size_t)blockIdx.x * NACC;
  if (tid < 144) {
    const int k = tid / 6;
    const int q = (tid % 6) * 4;
    float a0=0.f,a1=0.f,a2=0.f,a3=0.f,b0=0.f,b1=0.f,b2=0.f,b3=0.f;
    for (int t = 0; t < ROWS; t += 2) {
      float  pk0 = P[t * PSTRIDE + k];
      float4 pq0 = *(const float4*)(&P[t * PSTRIDE + q]);
      float  pk1 = P[(t + 1) * PSTRIDE + k];
      float4 pq1 = *(const float4*)(&P[(t + 1) * PSTRIDE + q]);
      a0 = fmaf(pk0, pq0.x, a0); a1 = fmaf(pk0, pq0.y, a1);
      a2 = fmaf(pk0, pq0.z, a2); a3 = fmaf(pk0, pq0.w, a3);
      b0 = fmaf(pk1, pq1.x, b0); b1 = fmaf(pk1, pq1.y, b1);
      b2 = fmaf(pk1, pq1.z, b2); b3 = fmaf(pk1, pq1.w, b3);
    }
    outp[k * K_ + q + 0] = a0 + b0;
    outp[k * K_ + q + 1] = a1 + b1;
    outp[k * K_ + q + 2] = a2 + b2;
    outp[k * K_ + q + 3] = a3 + b3;
  } else if (tid < 168) {
    const int k = tid - 144;
    float s0 = 0.f, s1 = 0.f;
    for (int t = 0; t < ROWS; t += 2) {
      s0 += P[t * PSTRIDE + k];
      s1 += P[(t + 1) * PSTRIDE + k];
    }
    outp[576 + k] = s0 + s1;
  }
}

__global__ __launch_bounds__(64, 1) void socpool_eig(
    const float* __restrict__ partial, float* __restrict__ out) {
  __shared__ float Amat[K_ * 25];
  __shared__ float Qs[K_ * 25];
  __shared__ float lv[K_];
  __shared__ float raw[NACC];
  __shared__ float Xc[K_ * PSTRIDE];  // column-exchange buffer
  const int tid = threadIdx.x;  // 64 threads = 1 wave
  const int b = blockIdx.x;

  // combine the 4 per-block partials
#pragma unroll
  for (int i = 0; i < 10; ++i) {
    int e = tid + (i << 6);
    if (e < NACC) {
      float v = 0.f;
#pragma unroll
      for (int jj = 0; jj < BPB; ++jj)
        v += partial[(size_t)(b * BPB + jj) * NACC + e];
      raw[e] = v;
    }
  }
  __syncthreads();

  const float inv_n   = 1.f / 1024.f;
  const float inv_nm1 = 1.f / (1023.f + 1e-6f);
  float cv[9];
#pragma unroll
  for (int i = 0; i < 9; ++i) {
    int e = tid + (i << 6);            // < 576 always
    int k = e / K_, l = e % K_;
    cv[i] = (raw[e] - raw[576 + k] * raw[576 + l] * inv_n) * inv_nm1;
    Amat[k * 25 + l] = cv[i];
  }
  __syncthreads();
  float tr = 0.f;
#pragma unroll
  for (int k = 0; k < K_; ++k) tr += Amat[k * 25 + k];
  float sym[9];
#pragma unroll
  for (int i = 0; i < 9; ++i) {
    int e = tid + (i << 6);
    int k = e / K_, l = e % K_;
    sym[i] = cv[i] + Amat[l * 25 + k];
  }
  __syncthreads();
  const float sc = 0.5f / (tr + 1e-6f);
#pragma unroll
  for (int i = 0; i < 9; ++i) {
    int e = tid + (i << 6);
    int k = e / K_, l = e % K_;
    Amat[k * 25 + l] = sym[i] * sc + ((k == l) ? 1e-4f : 0.f);
  }
  __syncthreads();

  // ---- one-sided Jacobi: lane j holds column j as float4 Gv[6] ----
  const int j = tid;
  float4 Gv[6];
#pragma unroll
  for (int q = 0; q < 6; ++q) {
    // A symmetric: column j == row j (row read; init-only, alignment moot)
    Gv[q].x = (j < K_) ? Amat[j * 25 + 4*q + 0] : 0.f;
    Gv[q].y = (j < K_) ? Amat[j * 25 + 4*q + 1] : 0.f;
    Gv[q].z = (j < K_) ? Amat[j * 25 + 4*q + 2] : 0.f;
    Gv[q].w = (j < K_) ? Amat[j * 25 + 4*q + 3] : 0.f;
  }

  for (int sweep = 0; sweep < SWEEPS; ++sweep) {
    for (int rr = 0; rr < 23; ++rr) {
      // circle-method round-robin: fixed player 23; inv(2) mod 23 = 12
      int partner;
      if (j == 23) {
        partner = (12 * rr) % 23;
      } else if (j < 23) {
        partner = rr - j;
        if (partner < 0) partner += 23;
        if (partner == j) partner = 23;
      } else {
        partner = j;  // idle lanes: identity rotation below
      }
      // exchange via LDS: 6 b128 writes + 6 b128 reads (stride 28 -> no
      // bank conflicts), instead of 25 latency-serialized ds_bpermute
      if (j < K_) {
#pragma unroll
        for (int q = 0; q < 6; ++q)
          *(float4*)(&Xc[j * PSTRIDE + (q << 2)]) = Gv[q];
      }
      __syncthreads();
      const int pcol = (partner < K_) ? partner : 0;
      float4 O[6];
#pragma unroll
      for (int q = 0; q < 6; ++q)
        O[q] = *(const float4*)(&Xc[pcol * PSTRIDE + (q << 2)]);
      // three dots, 12 independent FMA chains
      float a0=0.f,a1=0.f,a2=0.f,a3=0.f;   // nn  = G.G
      float b0=0.f,b1=0.f,b2=0.f,b3=0.f;   // nno = O.O
      float c0=0.f,c1=0.f,c2=0.f,c3=0.f;   // gpq = G.O
#pragma unroll
      for (int q = 0; q < 6; ++q) {
        a0 = fmaf(Gv[q].x, Gv[q].x, a0); a1 = fmaf(Gv[q].y, Gv[q].y, a1);
        a2 = fmaf(Gv[q].z, Gv[q].z, a2); a3 = fmaf(Gv[q].w, Gv[q].w, a3);
        b0 = fmaf(O[q].x, O[q].x, b0);   b1 = fmaf(O[q].y, O[q].y, b1);
        b2 = fmaf(O[q].z, O[q].z, b2);   b3 = fmaf(O[q].w, O[q].w, b3);
        c0 = fmaf(Gv[q].x, O[q].x, c0);  c1 = fmaf(Gv[q].y, O[q].y, c1);
        c2 = fmaf(Gv[q].z, O[q].z, c2);  c3 = fmaf(Gv[q].w, O[q].w, c3);
      }
      float nn  = (a0 + a1) + (a2 + a3);
      float nno = (b0 + b1) + (b2 + b3);
      float gpq = (c0 + c1) + (c2 + c3);
      const bool low = (j < partner);
      float app = low ? nn : nno;
      float aqq = low ? nno : nn;
      float cc = 1.f, ss = 0.f;
      if (j != partner && fabsf(gpq) > 1e-30f) {
        float tau = (aqq - app) / (2.f * gpq);
        float t = 1.f / (fabsf(tau) + sqrtf(1.f + tau * tau));
        if (tau < 0.f) t = -t;
        cc = 1.f / sqrtf(1.f + t * t);
        ss = t * cc;
      }
      float sg = low ? -ss : ss;  // p' = c p - s q ; q' = s p + c q
#pragma unroll
      for (int q = 0; q < 6; ++q) {
        Gv[q].x = fmaf(sg, O[q].x, cc * Gv[q].x);
        Gv[q].y = fmaf(sg, O[q].y, cc * Gv[q].y);
        Gv[q].z = fmaf(sg, O[q].z, cc * Gv[q].z);
        Gv[q].w = fmaf(sg, O[q].w, cc * Gv[q].w);
      }
      __syncthreads();  // Xc reuse next round
    }
  }

  // eigenvalues = column norms (A SPD), eigenvectors = normalized columns
  if (j < K_) {
    float n0=0.f,n1=0.f,n2=0.f,n3=0.f;
#pragma unroll
    for (int q = 0; q < 6; ++q) {
      n0 = fmaf(Gv[q].x, Gv[q].x, n0); n1 = fmaf(Gv[q].y, Gv[q].y, n1);
      n2 = fmaf(Gv[q].z, Gv[q].z, n2); n3 = fmaf(Gv[q].w, Gv[q].w, n3);
    }
    float lam = sqrtf((n0 + n1) + (n2 + n3));
    lv[j] = logf(fmaxf(lam, 1e-6f));
    float inv = 1.f / fmaxf(lam, 1e-20f);
#pragma unroll
    for (int q = 0; q < 6; ++q) {
      Qs[(4*q + 0) * 25 + j] = Gv[q].x * inv;
      Qs[(4*q + 1) * 25 + j] = Gv[q].y * inv;
      Qs[(4*q + 2) * 25 + j] = Gv[q].z * inv;
      Qs[(4*q + 3) * 25 + j] = Gv[q].w * inv;
    }
  }
  __syncthreads();

  // log_cov = Q diag(lv) Q^T, upper triangle row-major (matches triu_indices)
  for (int e = tid; e < NPAIR; e += 64) {
    int i = 0, base = 0;
    while (i < K_ - 1 && base + (K_ - i) <= e) { base += K_ - i; ++i; }
    int jj = i + (e - base);
    float sum = 0.f;
#pragma unroll
    for (int k = 0; k < K_; ++k)
      sum = fmaf(Qs[i * 25 + k] * lv[k], Qs[jj * 25 + k], sum);
    out[(size_t)b * NPAIR + e] = sum;
  }
}

extern "C" void kernel_launch(void* const* d_in, const int* in_sizes, int n_in,
                              void* d_out, int out_size, void* d_ws, size_t ws_size,
                              hipStream_t stream) {
  const float* x = (const float*)d_in[0];
  const float* W = (const float*)d_in[1];
  float* partial = (float*)d_ws;  // 512 * 600 * 4 = 1.2 MB
  float* out = (float*)d_out;
  hipLaunchKernelGGL(socpool_proj, dim3(B_ * BPB), dim3(256), 0, stream,
                     x, W, partial);
  hipLaunchKernelGGL(socpool_eig, dim3(B_), dim3(64), 0, stream,
                     partial, out);
}